// Round 9
// baseline (160.122 us; speedup 1.0000x reference)
//
#include <hip/hip_runtime.h>

#define NB 32
#define WAVES_PER_BLOCK 4

__device__ __forceinline__ float clamp01(float x) {
    return fminf(fmaxf(x, 0.0f), 1.0f);
}

// Scatter the lane's 4 m-layout W float4s into the padded LDS copy
// (row stride 33 -> conflict-free row reads in pass 1).
__device__ __forceinline__ void scatter_W(float* sw, const float4* wr, int lw) {
    const int g = lw >> 3;          // row within 8-row group
    const int c = (lw & 7) * 4;     // starting col
    #pragma unroll
    for (int k = 0; k < 4; ++k) {
        const int r = k * 8 + g;
        const float* wp = (const float*)&wr[k];
        sw[r * 33 + c + 0] = wp[0];
        sw[r * 33 + c + 1] = wp[1];
        sw[r * 33 + c + 2] = wp[2];
        sw[r * 33 + c + 3] = wp[3];
    }
}

// Full per-token work: pass 1 (inflow via LDS W copy), EPGL update,
// h_new publish (overlaid into the first 512B of the W LDS region, which
// is dead after pass 1), pass 2 (pairwise distance + W update from the
// lane's registers). All LDS touched here is wave-private.
__device__ __forceinline__ void process_token(
    const float* __restrict__ shin,   // input h for this token [NB*4]
    float*       swave,               // s_W[wave]: W copy + h_new overlay
    const float4* wr,                 // lane's 4 W float4s (m-layout)
    float sti, int lw,
    float* __restrict__ out_h_t,      // out_h + token*NB*4
    float4* __restrict__ outWt)       // out_W + token*NB*NB
{
    const int i    = lw & 31;         // row this lane owns in pass 1
    const int half = lw >> 5;         // j-range selector

    // ---- pass 1: inflow. lane (i, half) sums 16 j's ----
    float accE = 0.f, accP = 0.f, accG = 0.f, accL = 0.f, tot = 0.f;
    #pragma unroll
    for (int t = 0; t < 16; ++t) {
        const int j = half * 16 + t;
        float w = swave[i * 33 + j];
        w = (j == i) ? 0.0f : w;                 // zero self-connection
        const float4 hj = *(const float4*)&shin[j * 4];   // broadcast read
        accE = fmaf(w, hj.x, accE);
        accP = fmaf(w, hj.y, accP);
        accG = fmaf(w, hj.z, accG);
        accL = fmaf(w, hj.w, accL);
        tot += w;
    }
    accE += __shfl_xor(accE, 32);
    accP += __shfl_xor(accP, 32);
    accG += __shfl_xor(accG, 32);
    accL += __shfl_xor(accL, 32);
    tot  += __shfl_xor(tot,  32);

    const float inv = 1.0f / (tot + 1e-8f);
    const float En = accE * inv, Pn = accP * inv, Gn = accG * inv, Ln = accL * inv;

    // ---- EPGL state update (computed redundantly in both halves) ----
    const float4 hi = *(const float4*)&shin[i * 4];
    const float E = hi.x, P = hi.y, G = hi.z, L = hi.w;

    const float E_new = clamp01(E + 0.3f * sti - 0.4f * P - 0.2f * G);
    const float P_new = clamp01(P + 0.5f * sti + 0.3f * (Pn - P) - 0.2f * E);
    const float G_new = clamp01(G + 0.4f * E * (1.0f - P) + 0.2f * (Gn - G) - 0.3f * P);
    const float good  = 0.5f * En + 0.5f * Gn;
    const float L_new = clamp01(L + 0.4f * good + 0.3f * (Ln - L) - 0.3f * P);

    if (half == 0) {
        const float4 hn = make_float4(E_new, P_new, G_new, L_new);
        ((float4*)swave)[i] = hn;     // overlay: W LDS rows 0-3 dead after pass 1
        ((float4*)out_h_t)[i] = hn;
    }
    __builtin_amdgcn_wave_barrier();  // keep publish before pass-2 reads

    // ---- pass 2: W_new. pairwise distance + update, W from registers ----
    const float* shn = swave;         // h_new lives in overlay
    const int jb0 = (lw & 7) * 4;     // hj cols depend only on lw&7, not k
    float4 hjv[4];
    #pragma unroll
    for (int e = 0; e < 4; ++e) {
        hjv[e] = *(const float4*)&shn[(jb0 + e) * 4];
    }

    #pragma unroll
    for (int k = 0; k < 4; ++k) {
        const int m  = k * 64 + lw;       // float4 index in token's W
        const int r  = m >> 3;            // row
        const float4 hr = *(const float4*)&shn[r * 4];
        const float  Lr = hr.w;
        const float* wp = (const float*)&wr[k];
        float4 res;
        float* resp = &res.x;
        #pragma unroll
        for (int e = 0; e < 4; ++e) {
            const int j = jb0 + e;
            const float4 hj = hjv[e];
            const float dx = hr.x - hj.x;
            const float dy = hr.y - hj.y;
            const float dz = hr.z - hj.z;
            const float dw = hr.w - hj.w;
            const float sq = dx * dx + dy * dy + dz * dz + dw * dw;
            const float dist = sqrtf(sq);               // sqrt(0)=0 matches ref
            const float mutual = 0.5f * (Lr + hj.w);
            float wn = 0.95f * wp[e] + 0.1f * mutual * dist;
            wn = clamp01(wn);
            resp[e] = (j == r) ? 0.0f : wn;             // zero diagonal
        }
        outWt[m] = res;                   // coalesced 1KB/instr store
    }
}

// Sequential 2-token pipeline per wave: ALL global loads for tokens A and B
// issue at wave start, so B's loads are in flight under A's entire
// compute+store phase, and A's stores drain under B's compute. Unlike the
// failed interleaved version, A's registers die before B's compute starts
// -> peak live state ~52 VGPR, no spill at the lb(256,6) cap (~85).
__global__ __launch_bounds__(256, 6) void biotoken_step(
    const float* __restrict__ h,
    const float* __restrict__ W,
    const float* __restrict__ stim,
    float* __restrict__ out_h,
    float* __restrict__ out_W)
{
    const int lw   = threadIdx.x & 63;    // lane in wave
    const int wave = threadIdx.x >> 6;    // 0..3
    const int tokA = (blockIdx.x * WAVES_PER_BLOCK + wave) * 2;
    const int i    = lw & 31;

    __shared__ float s_hin[WAVES_PER_BLOCK][2][NB * 4];
    __shared__ float s_W  [WAVES_PER_BLOCK][NB * 33];   // +1 pad per row

    // ---- stage: both tokens' global loads issued up front ----
    const float4* WtA = (const float4*)(W + (size_t)tokA * (NB * NB));
    float4 wA[4], wB[4];
    wA[0] = WtA[0 * 64 + lw];
    wA[1] = WtA[1 * 64 + lw];
    wA[2] = WtA[2 * 64 + lw];
    wA[3] = WtA[3 * 64 + lw];
    wB[0] = WtA[256 + 0 * 64 + lw];       // token B = tokA+1, adjacent 4KB
    wB[1] = WtA[256 + 1 * 64 + lw];
    wB[2] = WtA[256 + 2 * 64 + lw];
    wB[3] = WtA[256 + 3 * 64 + lw];

    // h for both tokens in one shot: lanes 0-31 stage A, lanes 32-63 stage B
    {
        const int buf = lw >> 5;
        ((float4*)s_hin[wave][buf])[i] =
            ((const float4*)(h + (size_t)(tokA + buf) * (NB * 4)))[i];
    }
    const float stiA = stim[(size_t)tokA * NB + i];         // 128B broadcasts
    const float stiB = stim[(size_t)(tokA + 1) * NB + i];

    scatter_W(s_W[wave], wA, lw);
    __syncthreads();                      // phase-align the block's 4 waves

    // ---- token A (B's loads still in flight underneath) ----
    process_token(s_hin[wave][0], s_W[wave], wA, stiA, lw,
                  out_h + (size_t)tokA * (NB * 4),
                  (float4*)(out_W + (size_t)tokA * (NB * NB)));

    // ---- token B: rescatter LDS (waits wB loads), then process ----
    __builtin_amdgcn_wave_barrier();      // pass-2-A LDS reads before overwrite
    scatter_W(s_W[wave], wB, lw);
    __builtin_amdgcn_wave_barrier();
    process_token(s_hin[wave][1], s_W[wave], wB, stiB, lw,
                  out_h + (size_t)(tokA + 1) * (NB * 4),
                  (float4*)(out_W + (size_t)(tokA + 1) * (NB * NB)));
}

extern "C" void kernel_launch(void* const* d_in, const int* in_sizes, int n_in,
                              void* d_out, int out_size, void* d_ws, size_t ws_size,
                              hipStream_t stream) {
    const float* h    = (const float*)d_in[0];  // [8,2048,32,4]
    const float* W    = (const float*)d_in[1];  // [8,2048,32,32]
    const float* stim = (const float*)d_in[2];  // [8,2048,32]

    const int tokens = in_sizes[2] / NB;        // 16384
    float* out_h = (float*)d_out;               // [8,2048,32,4]
    float* out_W = (float*)d_out + (size_t)tokens * NB * 4;  // [8,2048,32,32]

    const int blocks = tokens / (WAVES_PER_BLOCK * 2); // 2048
    biotoken_step<<<blocks, 256, 0, stream>>>(h, W, stim, out_h, out_W);
}

// Round 10
// 138.408 us; speedup vs baseline: 1.1569x; 1.1569x over previous
//
#include <hip/hip_runtime.h>

#define NB 32
#define WAVES_PER_BLOCK 4
#define TOKENS_PER_WAVE 4

__device__ __forceinline__ float clamp01(float x) {
    return fminf(fmaxf(x, 0.0f), 1.0f);
}

// Async global->LDS DMA (gfx950). Each lane copies `size` bytes from its own
// global address to wave-uniform LDS base + lane*size. No VGPR round-trip,
// issued in program order (cannot be sunk/spilled like register prefetch).
__device__ __forceinline__ void gload_lds16(const float* g, float* lds) {
    __builtin_amdgcn_global_load_lds(
        (const __attribute__((address_space(1))) void*)g,
        (__attribute__((address_space(3))) void*)lds, 16, 0, 0);
}
__device__ __forceinline__ void gload_lds4(const float* g, float* lds) {
    __builtin_amdgcn_global_load_lds(
        (const __attribute__((address_space(1))) void*)g,
        (__attribute__((address_space(3))) void*)lds, 4, 0, 0);
}

// Stage one token's W (4KB, linear row-major) and h (512B) into LDS buffers.
__device__ __forceinline__ void stage_token(
    const float* __restrict__ W, const float* __restrict__ h,
    int token, float* bufW, float* bufH, int lw)
{
    const float* Wt = W + (size_t)token * (NB * NB);
    #pragma unroll
    for (int k = 0; k < 4; ++k) {
        // lane lw -> LDS bufW + k*1024B + lw*16B  ==  W row-major, m-layout
        gload_lds16(Wt + (size_t)(k * 64 + lw) * 4, bufW + k * 256);
    }
    const float* ht = h + (size_t)token * (NB * 4);
    gload_lds4(ht + lw,      bufH);        // floats 0..63
    gload_lds4(ht + 64 + lw, bufH + 64);   // floats 64..127
}

// 4 waves/block, each wave processes 4 sequential tokens with a
// double-buffered LDS pipeline: while token t computes, token t+1's W/h are
// DMA'd into the other buffer. The __syncthreads at each iteration top
// drains the DMA issued a full token-compute (~2000 cyc) earlier.
// Pass 1 reads linear W with a per-row rotation (jj = (t+i)&15) so each
// bank serves exactly 2 lanes (free); pass 2 reads W m-layout (contiguous
// b128, conflict-free). LDS 38.9KB/block -> 4 blocks/CU, all resident.
__global__ __launch_bounds__(256, 4) void biotoken_step(
    const float* __restrict__ h,
    const float* __restrict__ W,
    const float* __restrict__ stim,
    float* __restrict__ out_h,
    float* __restrict__ out_W)
{
    const int lw   = threadIdx.x & 63;    // lane in wave
    const int wave = threadIdx.x >> 6;    // 0..3
    const int tok0 = (blockIdx.x * WAVES_PER_BLOCK + wave) * TOKENS_PER_WAVE;
    const int i    = lw & 31;             // row this lane owns
    const int half = lw >> 5;             // column-half this lane owns

    __shared__ float s_W   [WAVES_PER_BLOCK][2][NB * NB];   // 2 x 4KB per wave
    __shared__ float s_hin [WAVES_PER_BLOCK][2][NB * 4];    // 2 x 512B
    __shared__ float s_hnew[WAVES_PER_BLOCK][NB * 4];       // 512B

    // ---- prologue: DMA token 0 into buffer 0; stim -> register ----
    stage_token(W, h, tok0, s_W[wave][0], s_hin[wave][0], lw);
    float stiC = stim[(size_t)tok0 * NB + i];   // 128B broadcast
    float stiN = 0.0f;

    #pragma unroll
    for (int tt = 0; tt < TOKENS_PER_WAVE; ++tt) {
        const int cur   = tt & 1;               // compile-time after unroll
        const int token = tok0 + tt;

        __syncthreads();   // drains DMA for buf[cur] (issued ~1 token ago)

        // ---- issue next token's DMA into the other buffer ----
        if (tt + 1 < TOKENS_PER_WAVE) {
            stage_token(W, h, token + 1, s_W[wave][cur ^ 1],
                        s_hin[wave][cur ^ 1], lw);
            stiN = stim[(size_t)(token + 1) * NB + i];
        }

        const float* bw   = s_W[wave][cur];     // linear row-major W
        const float* shin = s_hin[wave][cur];

        // ---- pass 1: inflow. lane (i, half) sums its 16 j's, rotated ----
        float accE = 0.f, accP = 0.f, accG = 0.f, accL = 0.f, tot = 0.f;
        #pragma unroll
        for (int t = 0; t < 16; ++t) {
            const int jj = (half << 4) | ((t + i) & 15);   // bank jj%32: 2 lanes each
            float w = bw[i * 32 + jj];
            w = (jj == i) ? 0.0f : w;                      // zero self-connection
            const float4 hj = *(const float4*)&shin[jj * 4];
            accE = fmaf(w, hj.x, accE);
            accP = fmaf(w, hj.y, accP);
            accG = fmaf(w, hj.z, accG);
            accL = fmaf(w, hj.w, accL);
            tot += w;
        }
        accE += __shfl_xor(accE, 32);
        accP += __shfl_xor(accP, 32);
        accG += __shfl_xor(accG, 32);
        accL += __shfl_xor(accL, 32);
        tot  += __shfl_xor(tot,  32);

        const float inv = 1.0f / (tot + 1e-8f);
        const float En = accE * inv, Pn = accP * inv;
        const float Gn = accG * inv, Ln = accL * inv;

        // ---- EPGL state update (redundant across halves) ----
        const float4 hi = *(const float4*)&shin[i * 4];
        const float E = hi.x, P = hi.y, G = hi.z, L = hi.w;

        const float E_new = clamp01(E + 0.3f * stiC - 0.4f * P - 0.2f * G);
        const float P_new = clamp01(P + 0.5f * stiC + 0.3f * (Pn - P) - 0.2f * E);
        const float G_new = clamp01(G + 0.4f * E * (1.0f - P) + 0.2f * (Gn - G) - 0.3f * P);
        const float good  = 0.5f * En + 0.5f * Gn;
        const float L_new = clamp01(L + 0.4f * good + 0.3f * (Ln - L) - 0.3f * P);

        if (half == 0) {
            const float4 hn = make_float4(E_new, P_new, G_new, L_new);
            ((float4*)s_hnew[wave])[i] = hn;
            ((float4*)(out_h + (size_t)token * (NB * 4)))[i] = hn;
        }
        __builtin_amdgcn_wave_barrier();   // publish before pass-2 reads (wave-private)

        // ---- pass 2: W_new. W from LDS m-layout (conflict-free b128) ----
        const float* shn = s_hnew[wave];
        float4* outWt = (float4*)(out_W + (size_t)token * (NB * NB));

        const int jb0 = (lw & 7) * 4;      // hj cols depend only on lw&7, not k
        float4 hjv[4];
        #pragma unroll
        for (int e = 0; e < 4; ++e) {
            hjv[e] = *(const float4*)&shn[(jb0 + e) * 4];
        }

        #pragma unroll
        for (int k = 0; k < 4; ++k) {
            const int m = k * 64 + lw;     // float4 index in token's W
            const int r = m >> 3;          // row
            const float4 wv = *(const float4*)&bw[(size_t)m * 4];  // lane's W float4
            const float4 hr = *(const float4*)&shn[r * 4];
            const float  Lr = hr.w;
            const float* wp = (const float*)&wv;
            float4 res;
            float* resp = &res.x;
            #pragma unroll
            for (int e = 0; e < 4; ++e) {
                const int j = jb0 + e;
                const float4 hj = hjv[e];
                const float dx = hr.x - hj.x;
                const float dy = hr.y - hj.y;
                const float dz = hr.z - hj.z;
                const float dw = hr.w - hj.w;
                const float sq = dx * dx + dy * dy + dz * dz + dw * dw;
                const float dist = sqrtf(sq);             // sqrt(0)=0 matches ref
                const float mutual = 0.5f * (Lr + hj.w);
                float wn = 0.95f * wp[e] + 0.1f * mutual * dist;
                wn = clamp01(wn);
                resp[e] = (j == r) ? 0.0f : wn;           // zero diagonal
            }
            outWt[m] = res;                // coalesced 1KB/instr store
        }

        stiC = stiN;
    }
}

extern "C" void kernel_launch(void* const* d_in, const int* in_sizes, int n_in,
                              void* d_out, int out_size, void* d_ws, size_t ws_size,
                              hipStream_t stream) {
    const float* h    = (const float*)d_in[0];  // [8,2048,32,4]
    const float* W    = (const float*)d_in[1];  // [8,2048,32,32]
    const float* stim = (const float*)d_in[2];  // [8,2048,32]

    const int tokens = in_sizes[2] / NB;        // 16384
    float* out_h = (float*)d_out;               // [8,2048,32,4]
    float* out_W = (float*)d_out + (size_t)tokens * NB * 4;  // [8,2048,32,32]

    const int blocks = tokens / (WAVES_PER_BLOCK * TOKENS_PER_WAVE); // 1024
    biotoken_step<<<blocks, 256, 0, stream>>>(h, W, stim, out_h, out_W);
}